// Round 7
// baseline (347.447 us; speedup 1.0000x reference)
//
#include <hip/hip_runtime.h>
#include <stdint.h>

typedef unsigned short u16;
typedef unsigned int   u32;
typedef unsigned long long u64;
typedef __attribute__((ext_vector_type(8))) short bf16x8;
typedef __attribute__((ext_vector_type(4))) float f32x4;

__device__ __forceinline__ float bflo(u32 u){ return __uint_as_float(u << 16); }
__device__ __forceinline__ u32 f2bf(float f){
  u32 u = __float_as_uint(f);
  return (u + 0x7fffu + ((u >> 16) & 1u)) >> 16;
}
__device__ __forceinline__ float qbf(float f){ return __uint_as_float(f2bf(f) << 16); }

// ---------- key builder: key = row<<32 | col<<13 | valcode13 (row-primary lexsort) ----------
__global__ void __launch_bounds__(256) k_keys_edges(
    const u16* __restrict__ emb, const u16* __restrict__ W1,
    const u16* __restrict__ b1, const u16* __restrict__ W2,
    const u16* __restrict__ b2,
    const int* __restrict__ src, const int* __restrict__ dst,
    const u16* __restrict__ eps_u, const u16* __restrict__ rb_u,
    u64* __restrict__ keys, int E, int ntiles)
{
  int lane = threadIdx.x & 63;
  int c    = lane & 15;
  int quad = lane >> 4;
  int wid  = blockIdx.x * 4 + (threadIdx.x >> 6);
  int wstride = gridDim.x * 4;

  bf16x8 bfr[4][4];
  #pragma unroll
  for (int ks = 0; ks < 4; ks++)
    #pragma unroll
    for (int t = 0; t < 4; t++)
      bfr[ks][t] = *(const bf16x8*)(W1 + (size_t)(t*16 + c)*128 + ks*32 + quad*8);

  float b1v[4], w2v[4];
  #pragma unroll
  for (int t = 0; t < 4; t++){
    b1v[t] = bflo((u32)b1[t*16 + c]);
    w2v[t] = bflo((u32)W2[t*16 + c]);
  }
  float b2v = bflo((u32)b2[0]);

  for (int tile = wid; tile < ntiles; tile += wstride){
    int e_base = tile * 16;
    int em = e_base + c; if (em >= E) em = E - 1;
    int s_m = src[em], d_m = dst[em];

    f32x4 acc0 = {0.f,0.f,0.f,0.f}, acc1 = {0.f,0.f,0.f,0.f};
    f32x4 acc2 = {0.f,0.f,0.f,0.f}, acc3 = {0.f,0.f,0.f,0.f};
    #pragma unroll
    for (int ks = 0; ks < 4; ks++){
      const u16* ap = emb + (size_t)(ks < 2 ? s_m : d_m) * 64 + (ks & 1) * 32 + quad * 8;
      bf16x8 a = *(const bf16x8*)ap;
      acc0 = __builtin_amdgcn_mfma_f32_16x16x32_bf16(a, bfr[ks][0], acc0, 0, 0, 0);
      acc1 = __builtin_amdgcn_mfma_f32_16x16x32_bf16(a, bfr[ks][1], acc1, 0, 0, 0);
      acc2 = __builtin_amdgcn_mfma_f32_16x16x32_bf16(a, bfr[ks][2], acc2, 0, 0, 0);
      acc3 = __builtin_amdgcn_mfma_f32_16x16x32_bf16(a, bfr[ks][3], acc3, 0, 0, 0);
    }
    float pr[4];
    #pragma unroll
    for (int r = 0; r < 4; r++){
      float h0 = fmaxf(acc0[r] + b1v[0], 0.f);
      float h1 = fmaxf(acc1[r] + b1v[1], 0.f);
      float h2 = fmaxf(acc2[r] + b1v[2], 0.f);
      float h3 = fmaxf(acc3[r] + b1v[3], 0.f);
      pr[r] = h0*w2v[0] + h1*w2v[1] + h2*w2v[2] + h3*w2v[3];
    }
    #pragma unroll
    for (int d = 1; d < 16; d <<= 1){
      #pragma unroll
      for (int r = 0; r < 4; r++) pr[r] += __shfl_xor(pr[r], d);
    }
    if (c < 4){
      int e = e_base + quad * 4 + c;
      if (e < E){
        float logit = ((c==0)?pr[0]:(c==1)?pr[1]:(c==2)?pr[2]:pr[3]) + b2v;
        float ue  = bflo((u32)eps_u[e]);
        float eps = fmaf(-0.9998f, ue, 0.9999f);
        float gate = logf(eps) - log1pf(-eps) + logit;
        float w = 1.f / (1.f + expf(-gate));
        float att = fminf(fmaxf(w, 0.01f), 0.99f);
        float uu  = fminf(fmaxf(bflo((u32)rb_u[e]), 1e-7f), 1.f - 1e-7f);
        float l = (logf(att) - log1pf(-att) + logf(uu) - log1pf(-uu)) * (1.f / 0.9f);
        float val = 1.f / (1.f + expf(-l));
        u32 h  = f2bf(val);                                  // RNE bf16 bits
        u32 code = (h >= 8192u) ? (h - 8192u) : 0u;          // 13-bit val code
        keys[e] = ((u64)(u32)src[e] << 32) | ((u64)(u32)dst[e] << 13) | (u64)code;
      }
    }
  }
}

// rand entries: val 0.05 -> bf16 0x3D4D -> code 15693-8192 = 7501
__global__ void k_keys_rand(const int* __restrict__ rand0, const int* __restrict__ rand1,
                            u64* __restrict__ keys, int E, int R){
  int i = blockIdx.x * 256 + threadIdx.x;
  if (i >= R) return;
  keys[E + i] = ((u64)(u32)rand0[i] << 32) | ((u64)(u32)rand1[i] << 13) | 7501ull;
}

// ---------- stable LSD radix sort: 5 passes x 8 bits over bits [13,53) ----------
__global__ void __launch_bounds__(256) k_rhist(const u64* __restrict__ keys,
                                               u32* __restrict__ hist,
                                               int M, int NB, int shift){
  __shared__ u32 bins[256];
  int t = threadIdx.x, b = blockIdx.x;
  bins[t] = 0;
  __syncthreads();
  #pragma unroll
  for (int k = 0; k < 4; k++){
    int i = b * 1024 + k * 256 + t;
    if (i < M){
      u32 d = (u32)(keys[i] >> shift) & 255u;
      atomicAdd(&bins[d], 1);
    }
  }
  __syncthreads();
  hist[(size_t)t * NB + b] = bins[t];
}

__global__ void k_rscanB(u32* __restrict__ hist, u32* __restrict__ dtot, int NB){
  __shared__ u32 sh[256];
  int d = blockIdx.x, t = threadIdx.x;
  u32 carry = 0;
  for (int c0 = 0; c0 < NB; c0 += 256){
    int idx = c0 + t;
    u32 v = (idx < NB) ? hist[(size_t)d * NB + idx] : 0;
    sh[t] = v;
    __syncthreads();
    for (int off = 1; off < 256; off <<= 1){
      u32 x = (t >= off) ? sh[t - off] : 0;
      __syncthreads();
      sh[t] += x;
      __syncthreads();
    }
    if (idx < NB) hist[(size_t)d * NB + idx] = sh[t] - v + carry;
    u32 tot = sh[255];
    __syncthreads();
    carry += tot;
  }
  if (t == 0) dtot[d] = carry;
}

__global__ void k_rscanC(const u32* __restrict__ dtot, u32* __restrict__ dbase){
  __shared__ u32 sh[256];
  int t = threadIdx.x;
  u32 v = dtot[t];
  sh[t] = v;
  __syncthreads();
  for (int off = 1; off < 256; off <<= 1){
    u32 x = (t >= off) ? sh[t - off] : 0;
    __syncthreads();
    sh[t] += x;
    __syncthreads();
  }
  dbase[t] = sh[t] - v;
}

// stable scatter, slot-major order, ballot-based ranks
__global__ void __launch_bounds__(256) k_rscatter(
    const u64* __restrict__ srck, u64* __restrict__ dstk,
    const u32* __restrict__ hist, const u32* __restrict__ dbase,
    int M, int NB, int shift){
  __shared__ u32 Rr[256];
  __shared__ u32 Wc[256][4];
  __shared__ u32 SB[256];
  int t = threadIdx.x, b = blockIdx.x;
  int w = t >> 6, l = t & 63;
  Rr[t] = 0;
  Wc[t][0] = Wc[t][1] = Wc[t][2] = Wc[t][3] = 0;
  SB[t] = dbase[t] + hist[(size_t)t * NB + b];
  __syncthreads();
  #pragma unroll
  for (int k = 0; k < 4; k++){
    int i = b * 1024 + k * 256 + t;
    bool valid = (i < M);
    u64 kk = valid ? srck[i] : 0;
    u32 d = (u32)(kk >> shift) & 255u;
    u64 vm = __ballot(valid ? 1 : 0);
    u64 m = ~0ull;
    #pragma unroll
    for (int bit = 0; bit < 8; bit++){
      u64 bb = __ballot((d >> bit) & 1);
      m &= ((d >> bit) & 1) ? bb : ~bb;
    }
    m &= vm;
    u64 ltmask = (l == 0) ? 0ull : (~0ull >> (64 - l));
    u32 before = (u32)__popcll(m & ltmask);
    if (valid && before == 0) Wc[d][w] = (u32)__popcll(m);
    __syncthreads();
    if (valid){
      u32 r = Rr[d] + before;
      #pragma unroll
      for (int w2 = 0; w2 < 3; w2++) if (w2 < w) r += Wc[d][w2];
      dstk[SB[d] + r] = kk;
    }
    __syncthreads();
    Rr[t] += Wc[t][0] + Wc[t][1] + Wc[t][2] + Wc[t][3];
    Wc[t][0] = Wc[t][1] = Wc[t][2] = Wc[t][3] = 0;
    __syncthreads();
  }
}

// ---------- emit FLOAT32: out = [rows_s | cols_s | vals], bf16-quantized values ----------
__global__ void k_emit(const u64* __restrict__ keys, float* __restrict__ out, int M){
  int i = blockIdx.x * 256 + threadIdx.x;
  if (i >= M) return;
  u64 k = keys[i];
  u32 row = (u32)(k >> 32);
  u32 col = (u32)(k >> 13) & 0x7FFFFu;
  u64 pair = k >> 13;
  out[i]     = qbf((float)row);
  out[M + i] = qbf((float)col);
  float v;
  if (i > 0 && (keys[i-1] >> 13) == pair){
    v = 0.f;                                 // duplicate: zeroed
  } else {
    u32 lo = (u32)k & 8191u;
    float sum = __uint_as_float((lo ? lo + 8192u : 0u) << 16);
    int j = i + 1;
    while (j < M && (keys[j] >> 13) == pair){
      u32 l2 = (u32)keys[j] & 8191u;
      sum += __uint_as_float((l2 ? l2 + 8192u : 0u) << 16);
      j++;
    }
    v = qbf(sum);
  }
  out[2 * M + i] = v;
}

extern "C" void kernel_launch(void* const* d_in, const int* in_sizes, int n_in,
                              void* d_out, int out_size, void* d_ws, size_t ws_size,
                              hipStream_t stream){
  (void)n_in; (void)out_size; (void)ws_size;
  const u16* all_emb = (const u16*)d_in[0];
  const u16* W1   = (const u16*)d_in[1];
  const u16* b1   = (const u16*)d_in[2];
  const u16* W2   = (const u16*)d_in[3];
  const u16* b2   = (const u16*)d_in[4];
  const int* edge_index = (const int*)d_in[5];
  const int* rand_idx   = (const int*)d_in[6];
  const u16* eps_u = (const u16*)d_in[7];
  const u16* rb_u  = (const u16*)d_in[8];

  int E = in_sizes[5] / 2;
  int R = in_sizes[6] / 2;
  int M = E + R;
  const int* src   = edge_index;
  const int* dst   = edge_index + E;
  const int* rand0 = rand_idx;
  const int* rand1 = rand_idx + R;

  int NB = (M + 1023) / 1024;

  // workspace: kb0[M] u64, kb1[M] u64, hist[256*NB] u32, dtot[256], dbase[256]
  u64* kb0  = (u64*)d_ws;
  u64* kb1  = kb0 + M;
  u32* hist = (u32*)(kb1 + M);
  u32* dtot = hist + (size_t)256 * NB;
  u32* dbase= dtot + 256;

  int ntiles = (E + 15) / 16;
  k_keys_edges<<<2048, 256, 0, stream>>>(all_emb, W1, b1, W2, b2, src, dst,
                                         eps_u, rb_u, kb0, E, ntiles);
  k_keys_rand<<<(R + 255) / 256, 256, 0, stream>>>(rand0, rand1, kb0, E, R);

  u64* s = kb0; u64* d = kb1;
  const int shifts[5] = {13, 21, 29, 37, 45};
  for (int p = 0; p < 5; p++){
    k_rhist   <<<NB, 256, 0, stream>>>(s, hist, M, NB, shifts[p]);
    k_rscanB  <<<256, 256, 0, stream>>>(hist, dtot, NB);
    k_rscanC  <<<1, 256, 0, stream>>>(dtot, dbase);
    k_rscatter<<<NB, 256, 0, stream>>>(s, d, hist, dbase, M, NB, shifts[p]);
    u64* tmp = s; s = d; d = tmp;
  }
  // after 5 passes, sorted data is in s (= kb1)
  k_emit<<<(M + 255) / 256, 256, 0, stream>>>(s, (float*)d_out, M);
}

// Round 10
// 289.461 us; speedup vs baseline: 1.2003x; 1.2003x over previous
//
#include <hip/hip_runtime.h>
#include <stdint.h>

typedef unsigned short u16;
typedef unsigned int   u32;
typedef __attribute__((ext_vector_type(8))) short bf16x8;
typedef __attribute__((ext_vector_type(4))) float f32x4;

__device__ __forceinline__ float bflo(u32 u){ return __uint_as_float(u << 16); }
__device__ __forceinline__ u32 f2bf(float f){
  u32 u = __float_as_uint(f);
  return (u + 0x7fffu + ((u >> 16) & 1u)) >> 16;
}
__device__ __forceinline__ float qbf(float f){ return __uint_as_float(f2bf(f) << 16); }

__global__ void k_zero(int* __restrict__ c, int N){
  int i = blockIdx.x * 256 + threadIdx.x;
  if (i < N) c[i] = 0;
}

// histogram all M rows
__global__ void k_hist(const int* __restrict__ src, const int* __restrict__ rand0,
                       int* __restrict__ cnt, int E, int M){
  int i = blockIdx.x * 256 + threadIdx.x;
  if (i >= M) return;
  int row = (i < E) ? src[i] : rand0[i - E];
  atomicAdd(&cnt[row], 1);
}

// exclusive scan over cnt[N]: block-local + block sums + add-back
__global__ void k_scan1(int* __restrict__ cnt, int* __restrict__ bsum, int N){
  __shared__ int sh[256];
  int blk = blockIdx.x, tid = threadIdx.x;
  int base = blk * 1024 + tid * 4;
  int v0 = (base + 0 < N) ? cnt[base + 0] : 0;
  int v1 = (base + 1 < N) ? cnt[base + 1] : 0;
  int v2 = (base + 2 < N) ? cnt[base + 2] : 0;
  int v3 = (base + 3 < N) ? cnt[base + 3] : 0;
  int tot = v0 + v1 + v2 + v3;
  sh[tid] = tot;
  __syncthreads();
  for (int off = 1; off < 256; off <<= 1){
    int t2 = (tid >= off) ? sh[tid - off] : 0;
    __syncthreads();
    sh[tid] += t2;
    __syncthreads();
  }
  int excl = sh[tid] - tot;
  if (base + 0 < N) cnt[base + 0] = excl;
  if (base + 1 < N) cnt[base + 1] = excl + v0;
  if (base + 2 < N) cnt[base + 2] = excl + v0 + v1;
  if (base + 3 < N) cnt[base + 3] = excl + v0 + v1 + v2;
  if (tid == 255) bsum[blk] = sh[255];
}

__global__ void k_scan2(const int* __restrict__ bsum, int* __restrict__ boff, int NB){
  __shared__ int sh[512];
  int tid = threadIdx.x;
  int v = (tid < NB) ? bsum[tid] : 0;
  sh[tid] = v;
  __syncthreads();
  for (int off = 1; off < 512; off <<= 1){
    int t2 = (tid >= off) ? sh[tid - off] : 0;
    __syncthreads();
    sh[tid] += t2;
    __syncthreads();
  }
  boff[tid] = sh[tid] - v;
}

__global__ void k_scan3(int* __restrict__ cnt, const int* __restrict__ boff, int N){
  int add = boff[blockIdx.x];
  int base = blockIdx.x * 1024 + threadIdx.x * 4;
  #pragma unroll
  for (int q = 0; q < 4; q++)
    if (base + q < N) cnt[base + q] += add;
}

// fused MFMA MLP + fast-math gate + atomic scatter of packed u32 (col<<13 | code13)
__global__ void __launch_bounds__(256) k_scatter_edges(
    const u16* __restrict__ emb, const u16* __restrict__ W1,
    const u16* __restrict__ b1, const u16* __restrict__ W2,
    const u16* __restrict__ b2,
    const int* __restrict__ src, const int* __restrict__ dst,
    const u16* __restrict__ eps_u, const u16* __restrict__ rb_u,
    int* __restrict__ cursor, u32* __restrict__ packed,
    int E, int ntiles)
{
  int lane = threadIdx.x & 63;
  int c    = lane & 15;
  int quad = lane >> 4;
  int wid  = blockIdx.x * 4 + (threadIdx.x >> 6);
  int wstride = gridDim.x * 4;

  bf16x8 bfr[4][4];
  #pragma unroll
  for (int ks = 0; ks < 4; ks++)
    #pragma unroll
    for (int t = 0; t < 4; t++)
      bfr[ks][t] = *(const bf16x8*)(W1 + (size_t)(t*16 + c)*128 + ks*32 + quad*8);

  float b1v[4], w2v[4];
  #pragma unroll
  for (int t = 0; t < 4; t++){
    b1v[t] = bflo((u32)b1[t*16 + c]);
    w2v[t] = bflo((u32)W2[t*16 + c]);
  }
  float b2v = bflo((u32)b2[0]);

  for (int tile = wid; tile < ntiles; tile += wstride){
    int e_base = tile * 16;
    int em = e_base + c; if (em >= E) em = E - 1;
    int s_m = src[em], d_m = dst[em];

    f32x4 acc0 = {0.f,0.f,0.f,0.f}, acc1 = {0.f,0.f,0.f,0.f};
    f32x4 acc2 = {0.f,0.f,0.f,0.f}, acc3 = {0.f,0.f,0.f,0.f};
    #pragma unroll
    for (int ks = 0; ks < 4; ks++){
      const u16* ap = emb + (size_t)(ks < 2 ? s_m : d_m) * 64 + (ks & 1) * 32 + quad * 8;
      bf16x8 a = *(const bf16x8*)ap;
      acc0 = __builtin_amdgcn_mfma_f32_16x16x32_bf16(a, bfr[ks][0], acc0, 0, 0, 0);
      acc1 = __builtin_amdgcn_mfma_f32_16x16x32_bf16(a, bfr[ks][1], acc1, 0, 0, 0);
      acc2 = __builtin_amdgcn_mfma_f32_16x16x32_bf16(a, bfr[ks][2], acc2, 0, 0, 0);
      acc3 = __builtin_amdgcn_mfma_f32_16x16x32_bf16(a, bfr[ks][3], acc3, 0, 0, 0);
    }
    float pr[4];
    #pragma unroll
    for (int r = 0; r < 4; r++){
      float h0 = fmaxf(acc0[r] + b1v[0], 0.f);
      float h1 = fmaxf(acc1[r] + b1v[1], 0.f);
      float h2 = fmaxf(acc2[r] + b1v[2], 0.f);
      float h3 = fmaxf(acc3[r] + b1v[3], 0.f);
      pr[r] = h0*w2v[0] + h1*w2v[1] + h2*w2v[2] + h3*w2v[3];
    }
    #pragma unroll
    for (int d = 1; d < 16; d <<= 1){
      #pragma unroll
      for (int r = 0; r < 4; r++) pr[r] += __shfl_xor(pr[r], d);
    }
    // lane handling edge e = e_base + quad*4 + c needs src/dst of THAT edge:
    // it lives in any lane whose (lane&15) == quad*4+c — shuffle from same 16-group.
    int srcl = (lane & 48) | (quad * 4 + (c & 3));
    int s_e = __shfl(s_m, srcl);
    int d_e = __shfl(d_m, srcl);
    if (c < 4){
      int e = e_base + quad * 4 + c;
      if (e < E){
        float logit = ((c==0)?pr[0]:(c==1)?pr[1]:(c==2)?pr[2]:pr[3]) + b2v;
        float ue  = bflo((u32)eps_u[e]);
        float eps = fmaf(-0.9998f, ue, 0.9999f);
        // gate = log(eps/(1-eps)) + logit  (hw log2)
        float gate = (__log2f(eps) - __log2f(1.0f - eps)) * 0.69314718f + logit;
        // log(clamp(sigmoid(gate),.01,.99)/(1-..)) == clamp(gate, +-log(99))
        gate = fminf(fmaxf(gate, -4.59511985f), 4.59511985f);
        float uu = fminf(fmaxf(bflo((u32)rb_u[e]), 1e-7f), 1.0f - 1e-7f);
        float lu = (__log2f(uu) - __log2f(1.0f - uu)) * 0.69314718f;
        float l  = (gate + lu) * (1.0f / 0.9f);
        float ee = __builtin_amdgcn_exp2f(-l * 1.44269504f);
        float val = 1.0f / (1.0f + ee);
        u32 h = f2bf(val);
        u32 code = (h >= 8192u) ? (h - 8192u) : 0u;
        int pos = atomicAdd(&cursor[s_e], 1);
        packed[pos] = ((u32)d_e << 13) | code;
      }
    }
  }
}

// rand entries: 0.05 -> bf16 0x3D4D -> code 15693-8192 = 7501
__global__ void k_scatter_rand(const int* __restrict__ rand0, const int* __restrict__ rand1,
                               int* __restrict__ cursor, u32* __restrict__ packed, int R){
  int i = blockIdx.x * 256 + threadIdx.x;
  if (i >= R) return;
  int pos = atomicAdd(&cursor[rand0[i]], 1);
  packed[pos] = ((u32)rand1[i] << 13) | 7501u;
}

// per-row insertion sort by packed (== by col), coalesce dups, emit FLOAT32
__global__ void k_emit(const int* __restrict__ cursor, u32* __restrict__ packed,
                       float* __restrict__ out, int N, int M){
  int r = blockIdx.x * 256 + threadIdx.x;
  if (r >= N) return;
  int b = (r == 0) ? 0 : cursor[r - 1];
  int e = cursor[r];
  for (int i = b + 1; i < e; i++){
    u32 p = packed[i];
    int j = i - 1;
    while (j >= b && packed[j] > p){ packed[j+1] = packed[j]; j--; }
    packed[j+1] = p;
  }
  float rf = qbf((float)r);
  int i = b;
  while (i < e){
    u32 p = packed[i];
    u32 col = p >> 13;
    u32 lo  = p & 8191u;
    float sum = __uint_as_float((lo ? lo + 8192u : 0u) << 16);
    int j = i + 1;
    while (j < e && (packed[j] >> 13) == col){
      u32 l2 = packed[j] & 8191u;
      sum += __uint_as_float((l2 ? l2 + 8192u : 0u) << 16);
      j++;
    }
    float cf = qbf((float)col);
    out[i] = rf; out[M + i] = cf; out[2 * M + i] = qbf(sum);
    for (int q = i + 1; q < j; q++){
      out[q] = rf; out[M + q] = cf; out[2 * M + q] = 0.f;
    }
    i = j;
  }
}

extern "C" void kernel_launch(void* const* d_in, const int* in_sizes, int n_in,
                              void* d_out, int out_size, void* d_ws, size_t ws_size,
                              hipStream_t stream){
  (void)n_in; (void)out_size; (void)ws_size;
  const u16* all_emb = (const u16*)d_in[0];
  const u16* W1   = (const u16*)d_in[1];
  const u16* b1   = (const u16*)d_in[2];
  const u16* W2   = (const u16*)d_in[3];
  const u16* b2   = (const u16*)d_in[4];
  const int* edge_index = (const int*)d_in[5];
  const int* rand_idx   = (const int*)d_in[6];
  const u16* eps_u = (const u16*)d_in[7];
  const u16* rb_u  = (const u16*)d_in[8];

  int N = in_sizes[0] / 64;
  int E = in_sizes[5] / 2;
  int R = in_sizes[6] / 2;
  int M = E + R;
  const int* src   = edge_index;
  const int* dst   = edge_index + E;
  const int* rand0 = rand_idx;
  const int* rand1 = rand_idx + R;

  // workspace: cnt[N] + bsum[512] + boff[512] + packed[M]  (~5.6 MB)
  int* cnt  = (int*)d_ws;
  int* bsum = cnt + N;
  int* boff = bsum + 512;
  u32* packed = (u32*)(boff + 512);

  k_zero<<<(N + 255) / 256, 256, 0, stream>>>(cnt, N);
  k_hist<<<(M + 255) / 256, 256, 0, stream>>>(src, rand0, cnt, E, M);
  int NB = (N + 1023) / 1024;
  k_scan1<<<NB, 256, 0, stream>>>(cnt, bsum, N);
  k_scan2<<<1, 512, 0, stream>>>(bsum, boff, NB);
  k_scan3<<<NB, 256, 0, stream>>>(cnt, boff, N);
  int ntiles = (E + 15) / 16;
  k_scatter_edges<<<2048, 256, 0, stream>>>(all_emb, W1, b1, W2, b2, src, dst,
                                            eps_u, rb_u, cnt, packed, E, ntiles);
  k_scatter_rand<<<(R + 255) / 256, 256, 0, stream>>>(rand0, rand1, cnt, packed, R);
  k_emit<<<(N + 255) / 256, 256, 0, stream>>>(cnt, packed, (float*)d_out, N, M);
}